// Round 1
// baseline (1451.996 us; speedup 1.0000x reference)
//
#include <hip/hip_runtime.h>
#include <math.h>

#define HWSZ 6400
#define WIMG 80
#define HIMG 80
#define BEPS 1e-5f

__device__ __forceinline__ float bn_silu(float a, float inv, float bet) {
    float t = fmaf(a, inv, bet);
    return t / (1.f + __expf(-t));
}

// ---------------- Kernel A: cv1 (1x1, 256->128) + bn1 + silu -> y1 ----------------
// grid: 8 * 100 blocks, 256 threads. Block tile: O=128, P=64. acc[32]/thread.
__global__ __launch_bounds__(256) void k_cv1(
    const float* __restrict__ x, const float* __restrict__ w,
    const float* __restrict__ g, const float* __restrict__ bb,
    const float* __restrict__ mm, const float* __restrict__ vv,
    float* __restrict__ y1)
{
    __shared__ float xt[64][64];
    int blk = blockIdx.x;
    int b = blk / 100, pt = blk % 100;
    int p0 = pt * 64;
    int tid = threadIdx.x;
    int p = tid & 63;
    int obase = __builtin_amdgcn_readfirstlane((tid >> 6) * 32);
    float acc[32];
#pragma unroll
    for (int i = 0; i < 32; ++i) acc[i] = 0.f;
    const float* xb = x + (size_t)b * 256 * HWSZ + p0;
    for (int cc = 0; cc < 256; cc += 64) {
        __syncthreads();
        for (int i = tid; i < 64 * 64; i += 256) {
            int c = i >> 6, pp = i & 63;
            xt[c][pp] = xb[(size_t)(cc + c) * HWSZ + pp];
        }
        __syncthreads();
#pragma unroll 4
        for (int c = 0; c < 64; ++c) {
            float xv = xt[c][p];
            const float* wrow = w + (size_t)obase * 256 + (cc + c);
#pragma unroll
            for (int i = 0; i < 32; ++i)
                acc[i] = fmaf(xv, wrow[(size_t)i * 256], acc[i]);
        }
    }
    float* yb = y1 + (size_t)b * 128 * HWSZ + p0 + p;
#pragma unroll
    for (int i = 0; i < 32; ++i) {
        int o = obase + i;
        float inv = g[o] * rsqrtf(vv[o] + BEPS);
        float bet = bb[o] - mm[o] * inv;
        yb[(size_t)o * HWSZ] = bn_silu(acc[i], inv, bet);
    }
}

// ---------------- Kernel B: 3x3 conv (128->27) + bias; sigmoid on mask channels ----
// grid: 8 * 25 blocks, 256 threads, thread per pixel, acc[27].
__global__ __launch_bounds__(256) void k_off(
    const float* __restrict__ y1, const float* __restrict__ w,
    const float* __restrict__ bias, float* __restrict__ raw)
{
    int blk = blockIdx.x;
    int b = blk / 25, pt = blk % 25;
    int p = pt * 256 + threadIdx.x;
    int h = p / WIMG, wx = p % WIMG;
    int idx[9];
#pragma unroll
    for (int n = 0; n < 9; ++n) {
        int yy = h - 1 + n / 3;
        int xx = wx - 1 + n % 3;
        bool valid = ((unsigned)yy < HIMG) && ((unsigned)xx < WIMG);
        idx[n] = valid ? (yy * WIMG + xx) : -1;
    }
    float acc[27];
#pragma unroll
    for (int o = 0; o < 27; ++o) acc[o] = 0.f;
    const float* yb = y1 + (size_t)b * 128 * HWSZ;
    for (int c = 0; c < 128; ++c) {
        const float* yc = yb + (size_t)c * HWSZ;
        float tv[9];
#pragma unroll
        for (int n = 0; n < 9; ++n) tv[n] = (idx[n] >= 0) ? yc[idx[n]] : 0.f;
        const float* wc = w + (size_t)c * 9;
#pragma unroll
        for (int o = 0; o < 27; ++o) {
#pragma unroll
            for (int n = 0; n < 9; ++n)
                acc[o] = fmaf(tv[n], wc[(size_t)o * 1152 + n], acc[o]);
        }
    }
    float* rb = raw + (size_t)b * 27 * HWSZ + p;
#pragma unroll
    for (int o = 0; o < 27; ++o) {
        float t = acc[o] + bias[o];
        if (o >= 18) t = 1.f / (1.f + __expf(-t));  // sigmoid for mask channels
        rb[(size_t)o * HWSZ] = t;
    }
}

// ---------------- Kernel C: DCNv2 + bn2 + silu -> z ----------------
// grid: 8 * 100 blocks, 256 threads. Block tile: O=128, P=64, K=1152 (c*9+n).
__global__ __launch_bounds__(256) void k_dcn(
    const float* __restrict__ y1, const float* __restrict__ raw,
    const float* __restrict__ w, const float* __restrict__ bias,
    const float* __restrict__ g, const float* __restrict__ bb,
    const float* __restrict__ mm, const float* __restrict__ vv,
    float* __restrict__ z)
{
    __shared__ int   sidx[4][9][64];
    __shared__ float swgt[4][9][64];
    __shared__ float sval[144][64];
    int blk = blockIdx.x;
    int b = blk / 100, pt = blk % 100;
    int p0 = pt * 64;
    int tid = threadIdx.x;

    // Stage 1: per (tap, pixel): 4 corner indices + weights (validity * bilinear * mask)
    for (int i = tid; i < 9 * 64; i += 256) {
        int n = i / 64, pp = i % 64;
        int p = p0 + pp;
        int h = p / WIMG, wx = p % WIMG;
        const float* rb = raw + (size_t)b * 27 * HWSZ + p;
        float dy = rb[(size_t)(2 * n) * HWSZ];
        float dx = rb[(size_t)(2 * n + 1) * HWSZ];
        float mk = rb[(size_t)(18 + n) * HWSZ];   // already sigmoided
        float py = (float)(h - 1 + n / 3) + dy;
        float px = (float)(wx - 1 + n % 3) + dx;
        float y0f = floorf(py), x0f = floorf(px);
        float fy = py - y0f, fx = px - x0f;
        int y0 = (int)y0f, x0 = (int)x0f;
#pragma unroll
        for (int k = 0; k < 4; ++k) {
            int yy = y0 + (k >> 1);
            int xx = x0 + (k & 1);
            bool valid = ((unsigned)yy < HIMG) && ((unsigned)xx < WIMG);
            float wk = ((k >> 1) ? fy : 1.f - fy) * ((k & 1) ? fx : 1.f - fx);
            wk = valid ? wk * mk : 0.f;
            int yc = min(max(yy, 0), HIMG - 1);
            int xc = min(max(xx, 0), WIMG - 1);
            sidx[k][n][pp] = yc * WIMG + xc;
            swgt[k][n][pp] = wk;
        }
    }

    int p = tid & 63;
    int obase = __builtin_amdgcn_readfirstlane((tid >> 6) * 32);
    float acc[32];
#pragma unroll
    for (int i = 0; i < 32; ++i) acc[i] = 0.f;
    const float* yb = y1 + (size_t)b * 128 * HWSZ;

    for (int cc = 0; cc < 128; cc += 16) {
        __syncthreads();
        // Stage 2a: build val tile [k=16c*9n][64p]
        for (int i = tid; i < 16 * 9 * 64; i += 256) {
            int pp = i & 63;
            int k = i >> 6;      // 0..143 = cl*9 + n
            int cl = k / 9, n = k % 9;
            const float* yc = yb + (size_t)(cc + cl) * HWSZ;
            float s = swgt[0][n][pp] * yc[sidx[0][n][pp]];
            s = fmaf(swgt[1][n][pp], yc[sidx[1][n][pp]], s);
            s = fmaf(swgt[2][n][pp], yc[sidx[2][n][pp]], s);
            s = fmaf(swgt[3][n][pp], yc[sidx[3][n][pp]], s);
            sval[k][pp] = s;
        }
        __syncthreads();
        // Stage 2b: FMA against scalar weights
        const float* wbase = w + (size_t)obase * 1152 + (size_t)cc * 9;
#pragma unroll 4
        for (int k = 0; k < 144; ++k) {
            float xv = sval[k][p];
#pragma unroll
            for (int i = 0; i < 32; ++i)
                acc[i] = fmaf(xv, wbase[(size_t)i * 1152 + k], acc[i]);
        }
    }

    float* zb = z + (size_t)b * 128 * HWSZ + p0 + p;
#pragma unroll
    for (int i = 0; i < 32; ++i) {
        int o = obase + i;
        float inv = g[o] * rsqrtf(vv[o] + BEPS);
        float bet = bb[o] - mm[o] * inv;
        zb[(size_t)o * HWSZ] = bn_silu(acc[i] + bias[o], inv, bet);
    }
}

// ---------------- Kernel D: cv2 (1x1, 128->256) + bn3 + silu + residual ----------------
// grid: 8 * 100 * 2 blocks, 256 threads. Block tile: O=128 (half), P=64.
__global__ __launch_bounds__(256) void k_cv2(
    const float* __restrict__ z, const float* __restrict__ x,
    const float* __restrict__ w,
    const float* __restrict__ g, const float* __restrict__ bb,
    const float* __restrict__ mm, const float* __restrict__ vv,
    float* __restrict__ out)
{
    __shared__ float zt[128][64];
    int blk = blockIdx.x;
    int b = blk / 200;
    int r = blk % 200;
    int pt = r >> 1, oh = r & 1;
    int p0 = pt * 64;
    int tid = threadIdx.x;
    for (int i = tid; i < 128 * 64; i += 256) {
        int c = i >> 6, pp = i & 63;
        zt[c][pp] = z[((size_t)b * 128 + c) * HWSZ + p0 + pp];
    }
    __syncthreads();
    int p = tid & 63;
    int obase = __builtin_amdgcn_readfirstlane((tid >> 6) * 32 + oh * 128);
    float acc[32];
#pragma unroll
    for (int i = 0; i < 32; ++i) acc[i] = 0.f;
#pragma unroll 4
    for (int c = 0; c < 128; ++c) {
        float zv = zt[c][p];
        const float* wrow = w + (size_t)obase * 128 + c;
#pragma unroll
        for (int i = 0; i < 32; ++i)
            acc[i] = fmaf(zv, wrow[(size_t)i * 128], acc[i]);
    }
    const float* xb = x + (size_t)b * 256 * HWSZ + p0 + p;
    float* ob = out + (size_t)b * 256 * HWSZ + p0 + p;
#pragma unroll
    for (int i = 0; i < 32; ++i) {
        int o = obase + i;
        float inv = g[o] * rsqrtf(vv[o] + BEPS);
        float bet = bb[o] - mm[o] * inv;
        ob[(size_t)o * HWSZ] = xb[(size_t)o * HWSZ] + bn_silu(acc[i], inv, bet);
    }
}

extern "C" void kernel_launch(void* const* d_in, const int* in_sizes, int n_in,
                              void* d_out, int out_size, void* d_ws, size_t ws_size,
                              hipStream_t stream) {
    const float* x     = (const float*)d_in[0];
    const float* cv1w  = (const float*)d_in[1];
    const float* bn1g  = (const float*)d_in[2];
    const float* bn1b  = (const float*)d_in[3];
    const float* bn1m  = (const float*)d_in[4];
    const float* bn1v  = (const float*)d_in[5];
    const float* offw  = (const float*)d_in[6];
    const float* offb  = (const float*)d_in[7];
    const float* dcnw  = (const float*)d_in[8];
    const float* dcnb  = (const float*)d_in[9];
    const float* bn2g  = (const float*)d_in[10];
    const float* bn2b  = (const float*)d_in[11];
    const float* bn2m  = (const float*)d_in[12];
    const float* bn2v  = (const float*)d_in[13];
    const float* cv2w  = (const float*)d_in[14];
    const float* bn3g  = (const float*)d_in[15];
    const float* bn3b  = (const float*)d_in[16];
    const float* bn3m  = (const float*)d_in[17];
    const float* bn3v  = (const float*)d_in[18];
    float* out = (float*)d_out;

    float* y1  = (float*)d_ws;                       // 8*128*6400
    float* raw = y1 + (size_t)8 * 128 * HWSZ;        // 8*27*6400
    float* z   = raw + (size_t)8 * 27 * HWSZ;        // 8*128*6400

    k_cv1<<<800, 256, 0, stream>>>(x, cv1w, bn1g, bn1b, bn1m, bn1v, y1);
    k_off<<<200, 256, 0, stream>>>(y1, offw, offb, raw);
    k_dcn<<<800, 256, 0, stream>>>(y1, raw, dcnw, dcnb, bn2g, bn2b, bn2m, bn2v, z);
    k_cv2<<<1600, 256, 0, stream>>>(z, x, cv2w, bn3g, bn3b, bn3m, bn3v, out);
}